// Round 1
// baseline (485.582 us; speedup 1.0000x reference)
//
#include <hip/hip_runtime.h>

// ParallelRetention  B=4 S=4096 F=128  gamma=0.96875
//
// Pipeline:
//  Kernel A (proj): q/k/v = x@W.T+b, rotary modulate -> Q'=[q*cos|q*sin],
//    K'=[k*cos|k*sin] stored TRANSPOSED per batch as Qt/Kt[b][kdim=256][s=4096]
//    (LDS-transposed, coalesced stores); V stored row-major [row][128].
//  Kernel B (retention): per (b, 64-s-row tile): sliding window of t
//    (gamma^512 ~ 8.7e-8 -> window 512 is exact to ~1e-6):
//      P[s][t] = sum_k Q'[s][k] * K'[t][k]   (k=0..255)
//      P *= gamma^(s-t) (0 if t>s);  out[s][f] += sum_t P[s][t]*V[t][f]
//    Q' and V are read via wave-uniform scalar loads (s_load, broadcast),
//    K' via coalesced vector loads (lanes<->t), P via padded LDS.
//
// fp32 everywhere this round (correctness anchor). VALU floor ~44us.

#define S_LEN 4096
#define B_N   4
#define F_N   128
#define WIN   512
#define LOG2_GAMMA (-0.0458036905705339f)

// ---------------------------------------------------------------------------
// Kernel A: projection + modulation + transpose.
// grid 512 blocks x 256 thr; block handles 32 rows of [B*S].
// lanes <-> output col o (0..127); rg = tid>>7 picks 16-row half.
__global__ __launch_bounds__(256)
void proj_kernel(const float* __restrict__ x,
                 const float* __restrict__ Wq, const float* __restrict__ bq,
                 const float* __restrict__ Wk, const float* __restrict__ bk,
                 const float* __restrict__ Wv, const float* __restrict__ bv,
                 const float* __restrict__ theta,
                 float* __restrict__ Qt, float* __restrict__ Kt,
                 float* __restrict__ V)
{
    __shared__ float tbuf[256 * 33];   // [kappa 0..255][srow 0..31], pad 33
    const int tid = threadIdx.x;
    const int o   = tid & 127;
    const int rg  = __builtin_amdgcn_readfirstlane(tid >> 7);  // wave-uniform
    const int r0  = blockIdx.x * 32;        // global row base
    const int b   = r0 >> 12;               // row / 4096
    const int s0  = r0 & (S_LEN - 1);

    float aq[16], ak[16], av[16];
#pragma unroll
    for (int r = 0; r < 16; ++r) { aq[r] = 0.f; ak[r] = 0.f; av[r] = 0.f; }

    const float* wqp = Wq + o * F_N;
    const float* wkp = Wk + o * F_N;
    const float* wvp = Wv + o * F_N;
    const float* xp  = x + (r0 + rg * 16) * F_N;   // wave-uniform base

    for (int ic = 0; ic < 32; ++ic) {
        float4 wq4 = *(const float4*)(wqp + ic * 4);   // per-lane gather
        float4 wk4 = *(const float4*)(wkp + ic * 4);
        float4 wv4 = *(const float4*)(wvp + ic * 4);
#pragma unroll
        for (int r = 0; r < 16; ++r) {
            float4 x4 = *(const float4*)(xp + r * F_N + ic * 4);  // s_load
            aq[r] = fmaf(x4.x, wq4.x, aq[r]);
            ak[r] = fmaf(x4.x, wk4.x, ak[r]);
            av[r] = fmaf(x4.x, wv4.x, av[r]);
            aq[r] = fmaf(x4.y, wq4.y, aq[r]);
            ak[r] = fmaf(x4.y, wk4.y, ak[r]);
            av[r] = fmaf(x4.y, wv4.y, av[r]);
            aq[r] = fmaf(x4.z, wq4.z, aq[r]);
            ak[r] = fmaf(x4.z, wk4.z, ak[r]);
            av[r] = fmaf(x4.z, wv4.z, av[r]);
            aq[r] = fmaf(x4.w, wq4.w, aq[r]);
            ak[r] = fmaf(x4.w, wk4.w, ak[r]);
            av[r] = fmaf(x4.w, wv4.w, av[r]);
        }
    }

    const float bqo = bq[o], bko = bk[o], bvo = bv[o], tho = theta[o];
    float qc[16], qs[16], kc[16], ks[16];
#pragma unroll
    for (int r = 0; r < 16; ++r) {
        const int srow = s0 + rg * 16 + r;
        const float ph = (float)(srow + 1) * tho;   // fp32 product, like ref
        float sn, cs;
        sincosf(ph, &sn, &cs);                      // accurate variant
        const float q = aq[r] + bqo;
        const float k = ak[r] + bko;
        const float v = av[r] + bvo;
        qc[r] = q * cs;  qs[r] = q * sn;
        kc[r] = k * cs;  ks[r] = k * sn;
        V[(r0 + rg * 16 + r) * F_N + o] = v;        // coalesced
    }

    // ---- transpose + store Q' ----
#pragma unroll
    for (int r = 0; r < 16; ++r) {
        tbuf[o * 33 + rg * 16 + r]           = qc[r];
        tbuf[(o + 128) * 33 + rg * 16 + r]   = qs[r];
    }
    __syncthreads();
    {
        float* qdst = Qt + (b * 256) * S_LEN + s0;
#pragma unroll
        for (int it = 0; it < 8; ++it) {
            const int F4  = tid + it * 256;   // 0..2047
            const int kap = F4 >> 3;          // 0..255
            const int sq  = (F4 & 7) * 4;     // 0..28
            float4 vv;
            vv.x = tbuf[kap * 33 + sq + 0];
            vv.y = tbuf[kap * 33 + sq + 1];
            vv.z = tbuf[kap * 33 + sq + 2];
            vv.w = tbuf[kap * 33 + sq + 3];
            *(float4*)(qdst + kap * S_LEN + sq) = vv;
        }
    }
    __syncthreads();
    // ---- transpose + store K' ----
#pragma unroll
    for (int r = 0; r < 16; ++r) {
        tbuf[o * 33 + rg * 16 + r]           = kc[r];
        tbuf[(o + 128) * 33 + rg * 16 + r]   = ks[r];
    }
    __syncthreads();
    {
        float* kdst = Kt + (b * 256) * S_LEN + s0;
#pragma unroll
        for (int it = 0; it < 8; ++it) {
            const int F4  = tid + it * 256;
            const int kap = F4 >> 3;
            const int sq  = (F4 & 7) * 4;
            float4 vv;
            vv.x = tbuf[kap * 33 + sq + 0];
            vv.y = tbuf[kap * 33 + sq + 1];
            vv.z = tbuf[kap * 33 + sq + 2];
            vv.w = tbuf[kap * 33 + sq + 3];
            *(float4*)(kdst + kap * S_LEN + sq) = vv;
        }
    }
}

// ---------------------------------------------------------------------------
// Kernel B: sliding-window retention.
// grid (S/64, B) x 512 thr (8 waves). s-tile = 64 rows; t-chunks of 128.
// P phase: wave w -> s-sub (w&3)*16..+15, t-half (w>>2)*64; lanes<->t.
// PV phase: lanes<->s (64), wave w -> f = w*16..w*16+15.
__global__ __launch_bounds__(512)
void retention_kernel(const float* __restrict__ Qt, const float* __restrict__ Kt,
                      const float* __restrict__ V, float* __restrict__ out)
{
    __shared__ float Ps[64 * 133];     // [s 0..63][t 0..127], pad 133 (odd)
    const int tid  = threadIdx.x;
    const int lane = tid & 63;
    const int w    = __builtin_amdgcn_readfirstlane(tid >> 6);  // 0..7
    const int b    = blockIdx.y;
    const int s0   = blockIdx.x * 64;

    const int t_start = (s0 >= WIN) ? ((s0 - WIN) & ~127) : 0;
    const int nch     = (s0 + 64 - t_start + 127) >> 7;

    const float* qbase = Qt + (b * 256) * S_LEN;
    const float* kbase = Kt + (b * 256) * S_LEN;
    const float* vbase = V  + b * S_LEN * F_N;

    const int sw = (w & 3) * 16;   // P-phase s sub-base
    const int th = (w >> 2) * 64;  // P-phase t half
    const int fb = w * 16;         // PV f base

    float oacc[16];
#pragma unroll
    for (int j = 0; j < 16; ++j) oacc[j] = 0.f;

    for (int ch = 0; ch < nch; ++ch) {
        const int tc = t_start + ch * 128;
        // ---------- P phase ----------
        {
            const int t   = tc + th + lane;
            const int tcl = (t < S_LEN) ? t : (S_LEN - 1);   // clamp loads
            float acc[16];
#pragma unroll
            for (int j = 0; j < 16; ++j) acc[j] = 0.f;
            const float* kp = kbase + tcl;       // per-lane (vector, coalesced)
            const float* qp = qbase + s0 + sw;   // wave-uniform (s_load)
            for (int k = 0; k < 256; ++k) {
                const float kv = kp[k * S_LEN];
                const float* qk = qp + k * S_LEN;
#pragma unroll
                for (int j = 0; j < 16; ++j)
                    acc[j] = fmaf(qk[j], kv, acc[j]);
            }
#pragma unroll
            for (int j = 0; j < 16; ++j) {
                const int e = (s0 + sw + j) - t;
                const float d = (e >= 0) ? exp2f((float)e * LOG2_GAMMA) : 0.f;
                Ps[(sw + j) * 133 + th + lane] = acc[j] * d;
            }
        }
        __syncthreads();
        // ---------- PV phase ----------
        {
            const int tend = (tc + 128 < s0 + 64) ? (tc + 128) : (s0 + 64);
            for (int t = tc; t < tend; ++t) {
                const float p = Ps[lane * 133 + (t - tc)];    // lanes<->s, 2-way max
                const float* vp = vbase + t * F_N + fb;       // wave-uniform (s_load)
#pragma unroll
                for (int j = 0; j < 16; ++j)
                    oacc[j] = fmaf(p, vp[j], oacc[j]);
            }
        }
        __syncthreads();
    }

    float* op = out + (b * S_LEN + s0 + lane) * F_N + fb;
#pragma unroll
    for (int u = 0; u < 4; ++u) {
        float4 vv;
        vv.x = oacc[4 * u + 0];
        vv.y = oacc[4 * u + 1];
        vv.z = oacc[4 * u + 2];
        vv.w = oacc[4 * u + 3];
        *(float4*)(op + 4 * u) = vv;
    }
}

// ---------------------------------------------------------------------------
extern "C" void kernel_launch(void* const* d_in, const int* in_sizes, int n_in,
                              void* d_out, int out_size, void* d_ws, size_t ws_size,
                              hipStream_t stream) {
    const float* x     = (const float*)d_in[0];
    const float* Wq    = (const float*)d_in[1];
    const float* bq    = (const float*)d_in[2];
    const float* Wk    = (const float*)d_in[3];
    const float* bk    = (const float*)d_in[4];
    const float* Wv    = (const float*)d_in[5];
    const float* bv    = (const float*)d_in[6];
    const float* theta = (const float*)d_in[7];
    float* out = (float*)d_out;

    float* ws = (float*)d_ws;
    float* Qt = ws;                    // [4][256][4096] = 4,194,304 floats
    float* Kt = ws + 4194304;          // same
    float* V  = ws + 8388608;          // [4][4096][128] = 2,097,152 floats
                                       // total 40 MiB of d_ws

    proj_kernel<<<512, 256, 0, stream>>>(x, Wq, bq, Wk, bk, Wv, bv, theta,
                                         Qt, Kt, V);
    retention_kernel<<<dim3(S_LEN / 64, B_N), 512, 0, stream>>>(Qt, Kt, V, out);
}

// Round 2
// 147.444 us; speedup vs baseline: 3.2933x; 3.2933x over previous
//
#include <hip/hip_runtime.h>

// ParallelRetention  B=4 S=4096 F=128  gamma=0.96875
// R2: retention via bf16 MFMA (16x16x32), proj stays fp32 VALU but emits
//     bf16 Qb/Kb [row][256] and Vt [b][f][4096] for the MFMA kernel.
// Window: gamma^512 ~ 8.7e-8 -> t-window 512 exact to ~1e-6.

#define S_LEN 4096
#define B_N   4
#define F_N   128
#define WIN   512
#define LOG2_GAMMA (-0.0458036905705339f)

typedef unsigned short u16;
typedef unsigned int   u32;
typedef __attribute__((ext_vector_type(8))) short bf16x8;   // 8 bf16 (4 VGPRs)
typedef __attribute__((ext_vector_type(4))) float f32x4;

__device__ inline u16 f2bf(float x) {
    u32 u = __builtin_bit_cast(u32, x);
    u32 r = (u + 0x7fffu + ((u >> 16) & 1u)) >> 16;
    return (u16)r;
}

// ---------------------------------------------------------------------------
// Kernel A: projection + rotary modulation; outputs bf16.
// grid 512 x 256; block = 32 rows of [B*S]; lanes <-> out col o.
__global__ __launch_bounds__(256)
void proj_kernel(const float* __restrict__ x,
                 const float* __restrict__ Wq, const float* __restrict__ bq,
                 const float* __restrict__ Wk, const float* __restrict__ bk,
                 const float* __restrict__ Wv, const float* __restrict__ bv,
                 const float* __restrict__ theta,
                 u16* __restrict__ Qb, u16* __restrict__ Kb,
                 u16* __restrict__ Vt)
{
    __shared__ float tbuf[256 * 33];   // [kappa 0..255][srow 0..31]
    const int tid = threadIdx.x;
    const int o   = tid & 127;
    const int rg  = __builtin_amdgcn_readfirstlane(tid >> 7);
    const int r0  = blockIdx.x * 32;
    const int b   = r0 >> 12;
    const int s0  = r0 & (S_LEN - 1);

    float aq[16], ak[16], av[16];
#pragma unroll
    for (int r = 0; r < 16; ++r) { aq[r] = 0.f; ak[r] = 0.f; av[r] = 0.f; }

    const float* wqp = Wq + o * F_N;
    const float* wkp = Wk + o * F_N;
    const float* wvp = Wv + o * F_N;
    const float* xp  = x + (r0 + rg * 16) * F_N;   // wave-uniform base

    for (int ic = 0; ic < 32; ++ic) {
        float4 wq4 = *(const float4*)(wqp + ic * 4);
        float4 wk4 = *(const float4*)(wkp + ic * 4);
        float4 wv4 = *(const float4*)(wvp + ic * 4);
#pragma unroll
        for (int r = 0; r < 16; ++r) {
            float4 x4 = *(const float4*)(xp + r * F_N + ic * 4);
            aq[r] = fmaf(x4.x, wq4.x, aq[r]);
            ak[r] = fmaf(x4.x, wk4.x, ak[r]);
            av[r] = fmaf(x4.x, wv4.x, av[r]);
            aq[r] = fmaf(x4.y, wq4.y, aq[r]);
            ak[r] = fmaf(x4.y, wk4.y, ak[r]);
            av[r] = fmaf(x4.y, wv4.y, av[r]);
            aq[r] = fmaf(x4.z, wq4.z, aq[r]);
            ak[r] = fmaf(x4.z, wk4.z, ak[r]);
            av[r] = fmaf(x4.z, wv4.z, av[r]);
            aq[r] = fmaf(x4.w, wq4.w, aq[r]);
            ak[r] = fmaf(x4.w, wk4.w, ak[r]);
            av[r] = fmaf(x4.w, wv4.w, av[r]);
        }
    }

    const float bqo = bq[o], bko = bk[o], bvo = bv[o], tho = theta[o];
    float qc[16], qs[16], kc[16], ksn[16], vv[16];
#pragma unroll
    for (int r = 0; r < 16; ++r) {
        const int srow = s0 + rg * 16 + r;
        const float ph = (float)(srow + 1) * tho;
        float sn, cs;
        sincosf(ph, &sn, &cs);
        const float q = aq[r] + bqo;
        const float k = ak[r] + bko;
        vv[r] = av[r] + bvo;
        qc[r] = q * cs;  qs[r] = q * sn;
        kc[r] = k * cs;  ksn[r] = k * sn;
    }

    // ---- Q' -> Qb [row][256] bf16 ----
#pragma unroll
    for (int r = 0; r < 16; ++r) {
        tbuf[o * 33 + rg * 16 + r]         = qc[r];
        tbuf[(o + 128) * 33 + rg * 16 + r] = qs[r];
    }
    __syncthreads();
#pragma unroll
    for (int it = 0; it < 4; ++it) {
        const int c  = it * 256 + tid;       // 0..1023
        const int s  = c >> 5;               // 0..31
        const int k0 = (c & 31) * 8;         // 0..248
        u32 p[4];
#pragma unroll
        for (int j = 0; j < 4; ++j) {
            u16 lo = f2bf(tbuf[(k0 + 2 * j) * 33 + s]);
            u16 hi = f2bf(tbuf[(k0 + 2 * j + 1) * 33 + s]);
            p[j] = (u32)lo | ((u32)hi << 16);
        }
        *(uint4*)(Qb + (r0 + s) * 256 + k0) = make_uint4(p[0], p[1], p[2], p[3]);
    }
    __syncthreads();
    // ---- K' -> Kb ----
#pragma unroll
    for (int r = 0; r < 16; ++r) {
        tbuf[o * 33 + rg * 16 + r]         = kc[r];
        tbuf[(o + 128) * 33 + rg * 16 + r] = ksn[r];
    }
    __syncthreads();
#pragma unroll
    for (int it = 0; it < 4; ++it) {
        const int c  = it * 256 + tid;
        const int s  = c >> 5;
        const int k0 = (c & 31) * 8;
        u32 p[4];
#pragma unroll
        for (int j = 0; j < 4; ++j) {
            u16 lo = f2bf(tbuf[(k0 + 2 * j) * 33 + s]);
            u16 hi = f2bf(tbuf[(k0 + 2 * j + 1) * 33 + s]);
            p[j] = (u32)lo | ((u32)hi << 16);
        }
        *(uint4*)(Kb + (r0 + s) * 256 + k0) = make_uint4(p[0], p[1], p[2], p[3]);
    }
    __syncthreads();
    // ---- V -> Vt [b][f][4096] bf16 (transposed) ----
#pragma unroll
    for (int r = 0; r < 16; ++r)
        tbuf[o * 33 + rg * 16 + r] = vv[r];
    __syncthreads();
#pragma unroll
    for (int it = 0; it < 2; ++it) {
        const int c = it * 256 + tid;        // 0..511
        const int f = c >> 2;                // 0..127
        const int u = c & 3;                 // 0..3 (8-elem chunk in s)
        u32 p[4];
#pragma unroll
        for (int j = 0; j < 4; ++j) {
            u16 lo = f2bf(tbuf[f * 33 + u * 8 + 2 * j]);
            u16 hi = f2bf(tbuf[f * 33 + u * 8 + 2 * j + 1]);
            p[j] = (u32)lo | ((u32)hi << 16);
        }
        *(uint4*)(Vt + b * (F_N * S_LEN) + f * S_LEN + s0 + u * 8) =
            make_uint4(p[0], p[1], p[2], p[3]);
    }
}

// ---------------------------------------------------------------------------
// Kernel B: MFMA sliding-window retention.
// grid (S/64, B) x 512 (8 waves). s-tile 64, t-chunks of 128.
// P: wave w -> s-sub (w&3)*16, t-half (w>>2)*64, 4 t-tiles x 8 ksteps.
// PV: wave w -> s-sub (w&3)*16, f-half (w>>2)*64, 4 f-tiles x 4 ksteps.
__global__ __launch_bounds__(512)
void retention_kernel(const u16* __restrict__ Qb, const u16* __restrict__ Kb,
                      const u16* __restrict__ Vt, float* __restrict__ out)
{
    __shared__ __align__(16) u16 K_lds[128 * 264];   // [t][256 + 8 pad]
    __shared__ __align__(16) u16 V_lds[128 * 136];   // [f][128 + 8 pad]
    __shared__ __align__(16) u16 P_lds[64 * 136];    // [s][128 + 8 pad]

    const int tid  = threadIdx.x;
    const int lane = tid & 63;
    const int w    = __builtin_amdgcn_readfirstlane(tid >> 6);
    const int b    = blockIdx.y;
    const int s0   = blockIdx.x * 64;

    const int t_start = (s0 >= WIN) ? ((s0 - WIN) & ~127) : 0;
    const int nch     = (s0 + 64 - t_start + 127) >> 7;

    const u16* Qbb = Qb + ((b << 12) + s0) * 256;
    const u16* Kbb = Kb + (b << 12) * 256;
    const u16* Vtb = Vt + b * (F_N * S_LEN);

    const int ssub = (w & 3) * 16;
    const int half = (w >> 2) * 64;       // t-half (P) / f-half (PV)
    const int col  = lane & 15;
    const int quad = lane >> 4;

    // Preload Q fragments: A[m=col][k=quad*8+j], 8 ksteps of 32.
    bf16x8 qf[8];
#pragma unroll
    for (int ks = 0; ks < 8; ++ks)
        qf[ks] = *(const bf16x8*)(Qbb + (ssub + col) * 256 + ks * 32 + quad * 8);

    f32x4 oacc[4];
#pragma unroll
    for (int ft = 0; ft < 4; ++ft) oacc[ft] = (f32x4){0.f, 0.f, 0.f, 0.f};

    for (int ch = 0; ch < nch; ++ch) {
        const int tc = t_start + (ch << 7);
        // ---- stage K chunk [128 t][256 k] ----
#pragma unroll
        for (int i = 0; i < 8; ++i) {
            const int c  = i * 512 + tid;
            const int t  = c >> 5;
            const int k0 = (c & 31) * 8;
            int trow = tc + t; if (trow > S_LEN - 1) trow = S_LEN - 1;
            uint4 v = *(const uint4*)(Kbb + trow * 256 + k0);
            *(uint4*)(K_lds + t * 264 + k0) = v;
        }
        // ---- stage V chunk [128 f][128 t] ----
#pragma unroll
        for (int i = 0; i < 4; ++i) {
            const int c = i * 512 + tid;
            const int f = c >> 4;
            const int u = c & 15;
            int tcol = tc + u * 8; if (tcol > S_LEN - 8) tcol = S_LEN - 8;
            uint4 v = *(const uint4*)(Vtb + f * S_LEN + tcol);
            *(uint4*)(V_lds + f * 136 + u * 8) = v;
        }
        __syncthreads();

        // ---- P = Q'K'^T, decay, -> P_lds bf16 ----
#pragma unroll
        for (int tt = 0; tt < 4; ++tt) {
            f32x4 acc = (f32x4){0.f, 0.f, 0.f, 0.f};
            const int tbase = half + tt * 16;
#pragma unroll
            for (int ks = 0; ks < 8; ++ks) {
                bf16x8 bfr = *(const bf16x8*)(K_lds + (tbase + col) * 264 +
                                              ks * 32 + quad * 8);
                acc = __builtin_amdgcn_mfma_f32_16x16x32_bf16(qf[ks], bfr, acc,
                                                              0, 0, 0);
            }
            const int tglob = tc + tbase + col;
#pragma unroll
            for (int r = 0; r < 4; ++r) {
                const int sglob = s0 + ssub + quad * 4 + r;
                const int e = sglob - tglob;
                const float d = (e >= 0) ? exp2f((float)e * LOG2_GAMMA) : 0.f;
                P_lds[(ssub + quad * 4 + r) * 136 + tbase + col] =
                    f2bf(acc[r] * d);
            }
        }
        __syncthreads();

        // ---- O += P V ----
#pragma unroll
        for (int ks = 0; ks < 4; ++ks) {
            bf16x8 pa = *(const bf16x8*)(P_lds + (ssub + col) * 136 +
                                         ks * 32 + quad * 8);
#pragma unroll
            for (int ft = 0; ft < 4; ++ft) {
                bf16x8 vb = *(const bf16x8*)(V_lds + (half + ft * 16 + col) * 136 +
                                             ks * 32 + quad * 8);
                oacc[ft] = __builtin_amdgcn_mfma_f32_16x16x32_bf16(pa, vb,
                                                                   oacc[ft],
                                                                   0, 0, 0);
            }
        }
        __syncthreads();
    }

    // ---- store O (C layout: row=quad*4+r, col=lane&15) ----
    float* ob = out + ((b << 12) + s0) * F_N;
#pragma unroll
    for (int ft = 0; ft < 4; ++ft) {
#pragma unroll
        for (int r = 0; r < 4; ++r) {
            ob[(ssub + quad * 4 + r) * F_N + half + ft * 16 + col] = oacc[ft][r];
        }
    }
}

// ---------------------------------------------------------------------------
extern "C" void kernel_launch(void* const* d_in, const int* in_sizes, int n_in,
                              void* d_out, int out_size, void* d_ws, size_t ws_size,
                              hipStream_t stream) {
    const float* x     = (const float*)d_in[0];
    const float* Wq    = (const float*)d_in[1];
    const float* bq    = (const float*)d_in[2];
    const float* Wk    = (const float*)d_in[3];
    const float* bk    = (const float*)d_in[4];
    const float* Wv    = (const float*)d_in[5];
    const float* bv    = (const float*)d_in[6];
    const float* theta = (const float*)d_in[7];
    float* out = (float*)d_out;

    u16* ws = (u16*)d_ws;
    u16* Qb = ws;                      // [4*4096][256] bf16 = 8 MiB
    u16* Kb = ws + 4194304;            // same
    u16* Vt = ws + 8388608;            // [4][128][4096] bf16 = 4 MiB

    proj_kernel<<<512, 256, 0, stream>>>(x, Wq, bq, Wk, bk, Wv, bv, theta,
                                         Qb, Kb, Vt);
    retention_kernel<<<dim3(S_LEN / 64, B_N), 512, 0, stream>>>(Qb, Kb, Vt, out);
}

// Round 3
// 115.991 us; speedup vs baseline: 4.1864x; 1.2712x over previous
//
#include <hip/hip_runtime.h>

// ParallelRetention  B=4 S=4096 F=128  gamma=0.96875
// R3: everything MFMA. prep tiles W into B-fragment order (WbF); proj is a
//     bf16 MFMA GEMM emitting fragment-ordered QbF/VtF + row-major Kb;
//     retention: s-tile 32, chunk 64, 2 blocks/CU, coalesced frag loads.
// Window: gamma^512 ~ 8.7e-8 -> t-window 512 exact to ~1e-6.

#define S_LEN 4096
#define B_N   4
#define F_N   128
#define WIN   512
#define LOG2_GAMMA (-0.0458036905705339f)

typedef unsigned short u16;
typedef unsigned int   u32;
typedef __attribute__((ext_vector_type(8))) short bf16x8;   // 8 bf16 (4 VGPRs)
typedef __attribute__((ext_vector_type(4))) float f32x4;

__device__ inline u16 f2bf(float x) {
    u32 u = __builtin_bit_cast(u32, x);
    u32 r = (u + 0x7fffu + ((u >> 16) & 1u)) >> 16;
    return (u16)r;
}

__device__ inline uint4 pack8(const u16* p) {
    uint4 v;
    v.x = (u32)p[0] | ((u32)p[1] << 16);
    v.y = (u32)p[2] | ((u32)p[3] << 16);
    v.z = (u32)p[4] | ((u32)p[5] << 16);
    v.w = (u32)p[6] | ((u32)p[7] << 16);
    return v;
}

// ---------------------------------------------------------------------------
// prep: W[3][128][128] fp32 -> WbF bf16 fragment order.
// WbF[fragid][lane*8+j] = W[mat][nt*16+(lane&15)][ks*32+(lane>>4)*8+j],
// fragid = mat*32 + nt*4 + ks.  grid 24 x 256.
__global__ void prep_kernel(const float* __restrict__ Wq,
                            const float* __restrict__ Wk,
                            const float* __restrict__ Wv,
                            u16* __restrict__ WbF)
{
    const int idx    = blockIdx.x * 256 + threadIdx.x;   // 0..6143
    const int lane   = idx & 63;
    const int fragid = idx >> 6;                         // 0..95
    const int ks     = fragid & 3;
    const int nt     = (fragid >> 2) & 7;
    const int mat    = fragid >> 5;
    const float* W = (mat == 0) ? Wq : (mat == 1 ? Wk : Wv);
    const float* src = W + (nt * 16 + (lane & 15)) * F_N + ks * 32 + (lane >> 4) * 8;
    float4 a = *(const float4*)src;
    float4 b = *(const float4*)(src + 4);
    u16 o[8] = {f2bf(a.x), f2bf(a.y), f2bf(a.z), f2bf(a.w),
                f2bf(b.x), f2bf(b.y), f2bf(b.z), f2bf(b.w)};
    *(uint4*)(WbF + fragid * 512 + lane * 8) = pack8(o);
}

// ---------------------------------------------------------------------------
// proj: grid 512 x 256 (4 waves). Block = 32 rows. wave w: m-tile mt=w&1,
// n-half nh=w>>1 (4 n-tiles). Outputs:
//   QbF[b][g=s>>4][ks0..7][lane*8]  (A-frag order, k=256)
//   Kb [b*4096+s][256]              (row-major, for LDS staging)
//   VtF[b][tb=s>>5][ft0..7][lane*8] (B-frag order, k=t)
__global__ __launch_bounds__(256, 2)
void proj_kernel(const float* __restrict__ x, const u16* __restrict__ WbF,
                 const float* __restrict__ bq, const float* __restrict__ bk,
                 const float* __restrict__ bv, const float* __restrict__ theta,
                 u16* __restrict__ QbF, u16* __restrict__ Kb,
                 u16* __restrict__ VtF)
{
    __shared__ __align__(16) u16 xb[32 * 136];     // [row][128+8]
    __shared__ __align__(16) u16 obuf[32 * 264];   // q/k: [32][256+8]; v: [128][40]

    const int tid  = threadIdx.x;
    const int lane = tid & 63;
    const int w    = __builtin_amdgcn_readfirstlane(tid >> 6);
    const int r0   = blockIdx.x * 32;
    const int b    = r0 >> 12;
    const int s0   = r0 & (S_LEN - 1);
    const int col  = lane & 15;
    const int quad = lane >> 4;
    const int mt   = w & 1;
    const int nh   = w >> 1;

    // ---- stage x (fp32 -> bf16) ----
#pragma unroll
    for (int it = 0; it < 4; ++it) {
        const int c   = it * 256 + tid;      // 0..1023
        const int row = c >> 5;
        const int k0  = (c & 31) * 4;
        float4 v = *(const float4*)(x + (r0 + row) * F_N + k0);
        u16 o[4] = {f2bf(v.x), f2bf(v.y), f2bf(v.z), f2bf(v.w)};
        *(uint2*)(xb + row * 136 + k0) =
            make_uint2((u32)o[0] | ((u32)o[1] << 16), (u32)o[2] | ((u32)o[3] << 16));
    }
    __syncthreads();

    // ---- A-frags ----
    bf16x8 af[4];
#pragma unroll
    for (int ks = 0; ks < 4; ++ks)
        af[ks] = *(const bf16x8*)(xb + (mt * 16 + col) * 136 + ks * 32 + quad * 8);

    // ---- MFMA: q, k, v ----
    f32x4 qa[4], ka[4], va[4];
#pragma unroll
    for (int nt = 0; nt < 4; ++nt) {
        qa[nt] = (f32x4){0.f, 0.f, 0.f, 0.f};
        ka[nt] = (f32x4){0.f, 0.f, 0.f, 0.f};
        va[nt] = (f32x4){0.f, 0.f, 0.f, 0.f};
    }
#pragma unroll
    for (int nt = 0; nt < 4; ++nt) {
        const int ng = nh * 4 + nt;
#pragma unroll
        for (int ks = 0; ks < 4; ++ks) {
            bf16x8 bqf = *(const bf16x8*)(WbF + ((0 * 8 + ng) * 4 + ks) * 512 + lane * 8);
            bf16x8 bkf = *(const bf16x8*)(WbF + ((1 * 8 + ng) * 4 + ks) * 512 + lane * 8);
            bf16x8 bvf = *(const bf16x8*)(WbF + ((2 * 8 + ng) * 4 + ks) * 512 + lane * 8);
            qa[nt] = __builtin_amdgcn_mfma_f32_16x16x32_bf16(af[ks], bqf, qa[nt], 0, 0, 0);
            ka[nt] = __builtin_amdgcn_mfma_f32_16x16x32_bf16(af[ks], bkf, ka[nt], 0, 0, 0);
            va[nt] = __builtin_amdgcn_mfma_f32_16x16x32_bf16(af[ks], bvf, va[nt], 0, 0, 0);
        }
    }

    // ---- per-lane bias/theta ----
    float bqv[4], bkv[4], bvv[4], thv[4];
#pragma unroll
    for (int nt = 0; nt < 4; ++nt) {
        const int o = nh * 64 + nt * 16 + col;
        bqv[nt] = bq[o]; bkv[nt] = bk[o]; bvv[nt] = bv[o]; thv[nt] = theta[o];
    }
    float cs[16], sn[16];
#pragma unroll
    for (int nt = 0; nt < 4; ++nt)
#pragma unroll
        for (int r = 0; r < 4; ++r) {
            const int srow = s0 + mt * 16 + quad * 4 + r;
            __sincosf((float)(srow + 1) * thv[nt], &sn[nt * 4 + r], &cs[nt * 4 + r]);
        }

    // ---- Q' -> obuf -> QbF ----
#pragma unroll
    for (int nt = 0; nt < 4; ++nt)
#pragma unroll
        for (int r = 0; r < 4; ++r) {
            const float q = qa[nt][r] + bqv[nt];
            const int row = mt * 16 + quad * 4 + r;
            const int o   = nh * 64 + nt * 16 + col;
            obuf[row * 264 + o]       = f2bf(q * cs[nt * 4 + r]);
            obuf[row * 264 + 128 + o] = f2bf(q * sn[nt * 4 + r]);
        }
    __syncthreads();
#pragma unroll
    for (int it = 0; it < 4; ++it) {
        const int c  = it * 256 + tid;           // 0..1023
        const int gl = c >> 9;                   // 0..1
        const int ks = (c >> 6) & 7;
        const int ln = c & 63;
        uint4 v = *(const uint4*)(obuf + (gl * 16 + (ln & 15)) * 264 +
                                  ks * 32 + (ln >> 4) * 8);
        *(uint4*)(QbF + (((b * 256 + (s0 >> 4) + gl) * 8 + ks) * 512) + ln * 8) = v;
    }
    __syncthreads();

    // ---- K' -> obuf -> Kb (row-major) ----
#pragma unroll
    for (int nt = 0; nt < 4; ++nt)
#pragma unroll
        for (int r = 0; r < 4; ++r) {
            const float k = ka[nt][r] + bkv[nt];
            const int row = mt * 16 + quad * 4 + r;
            const int o   = nh * 64 + nt * 16 + col;
            obuf[row * 264 + o]       = f2bf(k * cs[nt * 4 + r]);
            obuf[row * 264 + 128 + o] = f2bf(k * sn[nt * 4 + r]);
        }
    __syncthreads();
#pragma unroll
    for (int it = 0; it < 4; ++it) {
        const int c   = it * 256 + tid;
        const int row = c >> 5;
        const int k0  = (c & 31) * 8;
        uint4 v = *(const uint4*)(obuf + row * 264 + k0);
        *(uint4*)(Kb + (r0 + row) * 256 + k0) = v;
    }
    __syncthreads();

    // ---- V -> obuf[f][40] -> VtF ----
#pragma unroll
    for (int nt = 0; nt < 4; ++nt)
#pragma unroll
        for (int r = 0; r < 4; ++r) {
            const float vv = va[nt][r] + bvv[nt];
            const int f  = nh * 64 + nt * 16 + col;
            const int sl = mt * 16 + quad * 4 + r;
            obuf[f * 40 + sl] = f2bf(vv);
        }
    __syncthreads();
#pragma unroll
    for (int it = 0; it < 2; ++it) {
        const int c  = it * 256 + tid;           // 0..511
        const int ft = c >> 6;                   // 0..7
        const int ln = c & 63;
        uint4 v = *(const uint4*)(obuf + (ft * 16 + (ln & 15)) * 40 + (ln >> 4) * 8);
        *(uint4*)(VtF + ((b * 128 + (s0 >> 5)) * 8 + ft) * 512 + ln * 8) = v;
    }
}

// ---------------------------------------------------------------------------
// retention: grid (128, 4) x 256 (4 waves). s-tile 32, t-chunk 64.
// wave w: ssub=(w&1)*16; P: tt=(w>>1)*2+{0,1}; PV: f-half fh=w>>1.
__global__ __launch_bounds__(256, 2)
void retention_kernel(const u16* __restrict__ QbF, const u16* __restrict__ Kb,
                      const u16* __restrict__ VtF, float* __restrict__ out)
{
    __shared__ __align__(16) u16 K_lds[64 * 264];   // [t][256+8]
    __shared__ __align__(16) u16 P_lds[32 * 136];   // [s][128+8]

    const int tid  = threadIdx.x;
    const int lane = tid & 63;
    const int w    = __builtin_amdgcn_readfirstlane(tid >> 6);
    const int b    = blockIdx.y;
    const int s0   = blockIdx.x * 32;
    const int col  = lane & 15;
    const int quad = lane >> 4;
    const int ssub = (w & 1) * 16;
    const int fh   = w >> 1;

    const int t_start = (s0 >= WIN) ? ((s0 - WIN) & ~63) : 0;
    const int nch     = (s0 + 32 - t_start + 63) >> 6;

    const u16* Kbb = Kb + (b << 12) * 256;

    // Q A-frags (coalesced, fragment-ordered)
    const int g = ((s0 + ssub) >> 4);
    bf16x8 qf[8];
#pragma unroll
    for (int ks = 0; ks < 8; ++ks)
        qf[ks] = *(const bf16x8*)(QbF + ((b * 256 + g) * 8 + ks) * 512 + lane * 8);

    f32x4 oacc[4];
#pragma unroll
    for (int ft = 0; ft < 4; ++ft) oacc[ft] = (f32x4){0.f, 0.f, 0.f, 0.f};

    for (int ch = 0; ch < nch; ++ch) {
        const int tc = t_start + (ch << 6);
        // ---- stage K chunk [64 t][256 k] ----
#pragma unroll
        for (int i = 0; i < 8; ++i) {
            const int c  = i * 256 + tid;
            const int t  = c >> 5;
            const int k0 = (c & 31) * 8;
            int trow = tc + t; if (trow > S_LEN - 1) trow = S_LEN - 1;
            uint4 v = *(const uint4*)(Kbb + trow * 256 + k0);
            *(uint4*)(K_lds + t * 264 + k0) = v;
        }
        __syncthreads();

        // ---- P = Q'K'^T + decay -> P_lds ----
#pragma unroll
        for (int tp = 0; tp < 2; ++tp) {
            const int tt = fh * 2 + tp;
            f32x4 acc = (f32x4){0.f, 0.f, 0.f, 0.f};
#pragma unroll
            for (int ks = 0; ks < 8; ++ks) {
                bf16x8 bfr = *(const bf16x8*)(K_lds + (tt * 16 + col) * 264 +
                                              ks * 32 + quad * 8);
                acc = __builtin_amdgcn_mfma_f32_16x16x32_bf16(qf[ks], bfr, acc, 0, 0, 0);
            }
            const int tglob = tc + tt * 16 + col;
#pragma unroll
            for (int r = 0; r < 4; ++r) {
                const int sglob = s0 + ssub + quad * 4 + r;
                const int e = sglob - tglob;
                const float d = (e >= 0) ? exp2f((float)e * LOG2_GAMMA) : 0.f;
                P_lds[(ssub + quad * 4 + r) * 136 + tt * 16 + col] = f2bf(acc[r] * d);
            }
        }
        __syncthreads();

        // ---- O += P V  (V B-frags coalesced from VtF) ----
        bf16x8 pa[2];
#pragma unroll
        for (int ks = 0; ks < 2; ++ks)
            pa[ks] = *(const bf16x8*)(P_lds + (ssub + col) * 136 + ks * 32 + quad * 8);
#pragma unroll
        for (int ks = 0; ks < 2; ++ks) {
            int tb = (tc >> 5) + ks; if (tb > 127) tb = 127;   // decay zeroed
#pragma unroll
            for (int ft = 0; ft < 4; ++ft) {
                const int ftg = fh * 4 + ft;
                bf16x8 vb = *(const bf16x8*)(VtF + ((b * 128 + tb) * 8 + ftg) * 512 +
                                             lane * 8);
                oacc[ft] = __builtin_amdgcn_mfma_f32_16x16x32_bf16(pa[ks], vb,
                                                                   oacc[ft], 0, 0, 0);
            }
        }
        // next iteration's staging write to K_lds is safe: all waves passed
        // the P->PV barrier (K reads done); P_lds overwrite is gated by the
        // post-staging barrier.
    }

    float* ob = out + ((b << 12) + s0) * F_N;
#pragma unroll
    for (int ft = 0; ft < 4; ++ft)
#pragma unroll
        for (int r = 0; r < 4; ++r)
            ob[(ssub + quad * 4 + r) * F_N + fh * 64 + ft * 16 + col] = oacc[ft][r];
}

// ---------------------------------------------------------------------------
extern "C" void kernel_launch(void* const* d_in, const int* in_sizes, int n_in,
                              void* d_out, int out_size, void* d_ws, size_t ws_size,
                              hipStream_t stream) {
    const float* x     = (const float*)d_in[0];
    const float* Wq    = (const float*)d_in[1];
    const float* bq    = (const float*)d_in[2];
    const float* Wk    = (const float*)d_in[3];
    const float* bk    = (const float*)d_in[4];
    const float* Wv    = (const float*)d_in[5];
    const float* bv    = (const float*)d_in[6];
    const float* theta = (const float*)d_in[7];
    float* out = (float*)d_out;

    u16* ws  = (u16*)d_ws;
    u16* QbF = ws;                       // 4,194,304 u16 (8 MiB)
    u16* Kb  = ws + 4194304;             // 4,194,304 u16
    u16* VtF = ws + 8388608;             // 2,097,152 u16
    u16* WbF = ws + 10485760;            // 49,152 u16

    prep_kernel<<<24, 256, 0, stream>>>(Wq, Wk, Wv, WbF);
    proj_kernel<<<512, 256, 0, stream>>>(x, WbF, bq, bk, bv, theta, QbF, Kb, VtF);
    retention_kernel<<<dim3(128, B_N), 256, 0, stream>>>(QbF, Kb, VtF, out);
}